// Round 6
// baseline (253.759 us; speedup 1.0000x reference)
//
#include <hip/hip_runtime.h>

#define D 128

typedef __attribute__((ext_vector_type(8))) short short8;
typedef __attribute__((ext_vector_type(4))) float f32x4;

__device__ __forceinline__ unsigned int f2bf(float f) {
  unsigned int u = __float_as_uint(f);
  return (u + 0x7fffu + ((u >> 16) & 1u)) >> 16;   // RNE to bf16
}

// ---------------------------------------------------------------------------
// pre1: xbf conversion (blocks [0,XB)) + column histogram (blocks [XB,XB+HB))
// ---------------------------------------------------------------------------
__global__ __launch_bounds__(256) void pre1_k(
    const float* __restrict__ x, unsigned short* __restrict__ xbf, int n8,
    const int* __restrict__ ei, int* __restrict__ cursor, int E, int XB) {
  int b = blockIdx.x;
  if (b < XB) {
    int tid = b * 256 + threadIdx.x;
    if (tid >= n8) return;
    float4 a = ((const float4*)x)[(size_t)tid * 2];
    float4 c = ((const float4*)x)[(size_t)tid * 2 + 1];
    uint4 o;
    o.x = f2bf(a.x) | (f2bf(a.y) << 16);
    o.y = f2bf(a.z) | (f2bf(a.w) << 16);
    o.z = f2bf(c.x) | (f2bf(c.y) << 16);
    o.w = f2bf(c.z) | (f2bf(c.w) << 16);
    ((uint4*)xbf)[tid] = o;
  } else {
    int e = (b - XB) * 256 + threadIdx.x;
    if (e < E) atomicAdd(&cursor[ei[E + e]], 1);
  }
}

// ---------------------------------------------------------------------------
// CSR scan chain
// ---------------------------------------------------------------------------
__global__ __launch_bounds__(256) void scan_block_k(
    const int* __restrict__ deg, int* __restrict__ rowptr,
    int* __restrict__ partials, int Nn) {
  __shared__ int sdata[256];
  int t = threadIdx.x;
  int base = blockIdx.x * 1024 + t * 4;
  int v[4];
  #pragma unroll
  for (int j = 0; j < 4; ++j) v[j] = (base + j < Nn) ? deg[base + j] : 0;
  int tsum = v[0] + v[1] + v[2] + v[3];
  sdata[t] = tsum;
  __syncthreads();
  for (int off = 1; off < 256; off <<= 1) {
    int add = (t >= off) ? sdata[t - off] : 0;
    __syncthreads();
    sdata[t] += add;
    __syncthreads();
  }
  int run = sdata[t] - tsum;
  if (t == 255) partials[blockIdx.x] = sdata[255];
  #pragma unroll
  for (int j = 0; j < 4; ++j) {
    if (base + j < Nn) rowptr[base + j] = run;
    run += v[j];
  }
}

__global__ __launch_bounds__(128) void scan_partials_k(int* partials, int NB) {
  __shared__ int s[128];
  int t = threadIdx.x;
  int orig = (t < NB) ? partials[t] : 0;
  s[t] = orig;
  __syncthreads();
  for (int off = 1; off < 128; off <<= 1) {
    int add = (t >= off) ? s[t - off] : 0;
    __syncthreads();
    s[t] += add;
    __syncthreads();
  }
  if (t < NB) partials[t] = s[t] - orig;
}

// ---------------------------------------------------------------------------
// add_offsets (blocks [0,AB)) + W-pack/bias prep (blocks [AB,AB+128))
//   Bpack[((kt*8+nt)*64 + l)*8 + j] = Wt[kt*32 + (l>>4)*8 + j][nt*16 + (l&15)]
// ---------------------------------------------------------------------------
__global__ __launch_bounds__(256) void addoff_prep_k(
    int* __restrict__ rowptr, int* __restrict__ cursor,
    const int* __restrict__ partials,
    const float* __restrict__ W1, const float* __restrict__ b1,
    const float* __restrict__ W2, const float* __restrict__ b2,
    unsigned short* __restrict__ Bpack, float* __restrict__ bsum,
    int Nn, int E, int AB) {
  int b = blockIdx.x;
  if (b < AB) {
    int i = b * 256 + threadIdx.x;
    if (i < Nn) {
      int v = rowptr[i] + partials[i >> 10];
      rowptr[i] = v;
      cursor[i] = v;
    }
    if (i == 0) rowptr[Nn] = E;
  } else {
    int tid = (b - AB) * 256 + threadIdx.x;   // 0..32767
    if (tid < 32768) {
      int j = tid & 7;
      int l = (tid >> 3) & 63;
      int ktnt = tid >> 9;
      int kt = ktnt >> 3, nt = ktnt & 7;
      int k = kt * 32 + ((l >> 4) << 3) + j;
      int col = nt * 16 + (l & 15);
      float v = (k < 128) ? W1[col * 128 + k] : W2[col * 128 + (k - 128)];
      Bpack[tid] = (unsigned short)f2bf(v);
    }
    if (tid < 128) bsum[tid] = b1[tid] + b2[tid];
  }
}

__global__ __launch_bounds__(256) void fill_k(
    const int* __restrict__ ei, const float* __restrict__ ew,
    int* __restrict__ cursor, int2* __restrict__ edges, int E) {
  int e = blockIdx.x * 256 + threadIdx.x;
  if (e >= E) return;
  int c = ei[E + e];
  int p = atomicAdd(&cursor[c], 1);
  edges[p] = make_int2(ei[e], __float_as_int(ew[e]));
}

// ---------------------------------------------------------------------------
// aggfused: per 64-node tile — (1) each wave aggregates 16 nodes from bf16 x
// gathers (8 rows in flight, weight-masked clamp), computes u=agg+x, v=agg*x
// from f32 x, stages bf16 into LDS; (2) C[64x128]=U@Wt via MFMA; bias+lrelu.
// LDS row: bytes [0,256)=u (k 0..127), [256,512)=v (k 128..255); ROWB=528.
// A-frag: row=lane&15, k=(lane>>4)*8+j. C: col=lane&15, row=(lane>>4)*4+r.
// ---------------------------------------------------------------------------
__global__ __launch_bounds__(256, 4) void aggfused_k(
    const unsigned short* __restrict__ xbf, const float* __restrict__ x,
    const int* __restrict__ rowptr, const int2* __restrict__ edges,
    const unsigned short* __restrict__ Bpack, const float* __restrict__ bsum,
    float* __restrict__ out, int Nn) {
  constexpr int ROWB = 528;
  __shared__ __align__(16) unsigned char Us[64 * ROWB];
  const int t = threadIdx.x;
  const int node0 = blockIdx.x * 64;
  const int lane = t & 63, w = t >> 6;

  // ---- phase 1: aggregate + stage. Wave w owns nodes [w*16, w*16+16).
  for (int i = 0; i < 16; ++i) {
    int node = w * 16 + i;
    int g = node0 + node;
    uint up = 0, vp = 0;
    if (g < Nn) {
      float ax = 0.f, ay = 0.f;
      int beg = rowptr[g], end = rowptr[g + 1];
      for (int p = beg; p < end; p += 8) {
        int2 e[8];
        #pragma unroll
        for (int q = 0; q < 8; ++q) e[q] = edges[min(p + q, end - 1)];
        unsigned int v[8];
        #pragma unroll
        for (int q = 0; q < 8; ++q)
          v[q] = *(const unsigned int*)(xbf + (size_t)e[q].x * D + lane * 2);
        #pragma unroll
        for (int q = 0; q < 8; ++q) {
          float wt = (p + q < end) ? __int_as_float(e[q].y) : 0.f;
          ax += wt * __uint_as_float(v[q] << 16);
          ay += wt * __uint_as_float(v[q] & 0xffff0000u);
        }
      }
      float2 xr = *(const float2*)(x + (size_t)g * D + lane * 2);
      up = f2bf(ax + xr.x) | (f2bf(ay + xr.y) << 16);
      vp = f2bf(ax * xr.x) | (f2bf(ay * xr.y) << 16);
    }
    *(unsigned int*)(Us + node * ROWB + lane * 4)       = up;
    *(unsigned int*)(Us + node * ROWB + 256 + lane * 4) = vp;
  }
  __syncthreads();

  // ---- phase 2: MFMA
  const int c15 = lane & 15, kq = lane >> 4;

  short8 afr[8];
  const unsigned char* abase = Us + (size_t)(w * 16 + c15) * ROWB + kq * 16;
  #pragma unroll
  for (int kt = 0; kt < 8; ++kt)
    afr[kt] = *(const short8*)(abase + kt * 64);

  f32x4 acc[8];
  #pragma unroll
  for (int nt = 0; nt < 8; ++nt) acc[nt] = (f32x4){0.f, 0.f, 0.f, 0.f};

  const short8* bp = (const short8*)Bpack + lane;
  #pragma unroll
  for (int kt = 0; kt < 8; ++kt) {
    #pragma unroll
    for (int nt = 0; nt < 8; ++nt) {
      short8 bfr = bp[(kt * 8 + nt) * 64];
      acc[nt] = __builtin_amdgcn_mfma_f32_16x16x32_bf16(afr[kt], bfr, acc[nt], 0, 0, 0);
    }
  }

  float bsv[8];
  #pragma unroll
  for (int nt = 0; nt < 8; ++nt) bsv[nt] = bsum[nt * 16 + c15];

  #pragma unroll
  for (int r = 0; r < 4; ++r) {
    int g = node0 + w * 16 + kq * 4 + r;
    if (g >= Nn) continue;
    float* orow = out + (size_t)g * D + c15;
    #pragma unroll
    for (int nt = 0; nt < 8; ++nt) {
      float h = acc[nt][r] + bsv[nt];
      orow[nt * 16] = h > 0.f ? h : 0.2f * h;
    }
  }
}

// ---------------------------------------------------------------------------
extern "C" void kernel_launch(void* const* d_in, const int* in_sizes, int n_in,
                              void* d_out, int out_size, void* d_ws, size_t ws_size,
                              hipStream_t stream) {
  const float* x  = (const float*)d_in[0];
  const int*   ei = (const int*)d_in[1];
  const float* ew = (const float*)d_in[2];
  const float* W1 = (const float*)d_in[3];
  const float* b1 = (const float*)d_in[4];
  const float* W2 = (const float*)d_in[5];
  const float* b2 = (const float*)d_in[6];
  float* out = (float*)d_out;

  const int Nn = in_sizes[0] / D;   // 100000
  const int E  = in_sizes[2];       // 600000
  const int NB = (Nn + 1023) / 1024;

  const size_t xbfB    = (((size_t)Nn * D * 2) + 255) & ~(size_t)255;
  const size_t edgesB  = (size_t)E * sizeof(int2);
  const size_t cursorB = (((size_t)Nn * 4) + 255) & ~(size_t)255;
  const size_t rowptrB = (((size_t)(Nn + 1) * 4) + 255) & ~(size_t)255;
  const size_t partB   = 1024;
  const size_t BpackB  = 65536;

  char* base = (char*)d_ws;
  unsigned short* xbf   = (unsigned short*)base;  base += xbfB;
  int2*  edges   = (int2*)base;                   base += edgesB;
  int*   cursor  = (int*)base;                    base += cursorB;
  int*   rowptr  = (int*)base;                    base += rowptrB;
  int*   partials= (int*)base;                    base += partB;
  unsigned short* Bpack = (unsigned short*)base;  base += BpackB;
  float* bs      = (float*)base;

  hipMemsetAsync(cursor, 0, (size_t)Nn * 4, stream);

  const int n8 = Nn * D / 8;
  const int XB = (n8 + 255) / 256;
  const int HB = (E + 255) / 256;
  pre1_k<<<XB + HB, 256, 0, stream>>>(x, xbf, n8, ei, cursor, E, XB);

  scan_block_k<<<NB, 256, 0, stream>>>(cursor, rowptr, partials, Nn);
  scan_partials_k<<<1, 128, 0, stream>>>(partials, NB);

  const int AB = (Nn + 255) / 256;
  addoff_prep_k<<<AB + 128, 256, 0, stream>>>(rowptr, cursor, partials,
                                              W1, b1, W2, b2, Bpack, bs,
                                              Nn, E, AB);

  fill_k<<<HB, 256, 0, stream>>>(ei, ew, cursor, edges, E);

  aggfused_k<<<(Nn + 63) / 64, 256, 0, stream>>>(xbf, x, rowptr, edges,
                                                 Bpack, bs, out, Nn);
}

// Round 7
// 218.753 us; speedup vs baseline: 1.1600x; 1.1600x over previous
//
#include <hip/hip_runtime.h>

#define D 128

typedef __attribute__((ext_vector_type(8))) short short8;
typedef __attribute__((ext_vector_type(4))) float f32x4;

struct OvfE { int dst, row; float w; };

__device__ __forceinline__ unsigned int f2bf(float f) {
  unsigned int u = __float_as_uint(f);
  return (u + 0x7fffu + ((u >> 16) & 1u)) >> 16;   // RNE to bf16
}

// ---------------------------------------------------------------------------
// pre: blocks [0,XB) x->bf16 | [XB,XB+FB) slot-fill | [XB+FB,+128) W-pack/bias
// Slot-fill: p=atomicAdd(deg[c]); p<cap -> slots[c*cap+p]=(row,w), else
// overflow list (scanned by aggfused on the deg>cap path; cap chosen so this
// is ~never taken for Poisson(6) degrees).
// ---------------------------------------------------------------------------
__global__ __launch_bounds__(256) void pre_k(
    const float* __restrict__ x, unsigned short* __restrict__ xbf, int n8, int XB,
    const int* __restrict__ ei, const float* __restrict__ ew,
    int* __restrict__ deg, int* __restrict__ ovfcnt,
    int2* __restrict__ slots, OvfE* __restrict__ ovf, int ovfcap,
    int capLog2, int E, int FB,
    const float* __restrict__ W1, const float* __restrict__ b1,
    const float* __restrict__ W2, const float* __restrict__ b2,
    unsigned short* __restrict__ Bpack, float* __restrict__ bsum) {
  int b = blockIdx.x;
  if (b < XB) {
    int tid = b * 256 + threadIdx.x;
    if (tid >= n8) return;
    float4 a = ((const float4*)x)[(size_t)tid * 2];
    float4 c = ((const float4*)x)[(size_t)tid * 2 + 1];
    uint4 o;
    o.x = f2bf(a.x) | (f2bf(a.y) << 16);
    o.y = f2bf(a.z) | (f2bf(a.w) << 16);
    o.z = f2bf(c.x) | (f2bf(c.y) << 16);
    o.w = f2bf(c.z) | (f2bf(c.w) << 16);
    ((uint4*)xbf)[tid] = o;
  } else if (b < XB + FB) {
    int e = (b - XB) * 256 + threadIdx.x;
    if (e >= E) return;
    int c = ei[E + e];
    int p = atomicAdd(&deg[c], 1);
    if (p < (1 << capLog2)) {
      slots[((size_t)c << capLog2) + p] = make_int2(ei[e], __float_as_int(ew[e]));
    } else {
      int oi = atomicAdd(ovfcnt, 1);
      if (oi < ovfcap) { ovf[oi].dst = c; ovf[oi].row = ei[e]; ovf[oi].w = ew[e]; }
    }
  } else {
    int tid = (b - XB - FB) * 256 + threadIdx.x;   // 0..32767
    if (tid < 32768) {
      int j = tid & 7;
      int l = (tid >> 3) & 63;
      int ktnt = tid >> 9;
      int kt = ktnt >> 3, nt = ktnt & 7;
      int k = kt * 32 + ((l >> 4) << 3) + j;
      int col = nt * 16 + (l & 15);
      float v = (k < 128) ? W1[col * 128 + k] : W2[col * 128 + (k - 128)];
      Bpack[tid] = (unsigned short)f2bf(v);
    }
    if (tid < 128) bsum[tid] = b1[tid] + b2[tid];
  }
}

// ---------------------------------------------------------------------------
// aggfused: 64-node tile. Phase 1: half-wave (32 lanes x 4 dims) per node,
// 2 nodes in flight per wave, 8-deep edge batches (16 gathers in flight per
// wave); degree prefetched via lanes 0..15 + shfl. u=agg+x, v=agg*x -> bf16
// LDS. Phase 2: C[64x128]=U@Wt via mfma_f32_16x16x32_bf16; bias+leakyrelu.
// LDS row: [0,256)=u, [256,512)=v; ROWB=528. A: row=lane&15, k=(lane>>4)*8+j.
// C: col=lane&15, row=(lane>>4)*4+r (m89-verified).
// ---------------------------------------------------------------------------
__global__ __launch_bounds__(256, 4) void aggfused_k(
    const unsigned short* __restrict__ xbf, const float* __restrict__ x,
    const int* __restrict__ deg, const int2* __restrict__ slots,
    const int* __restrict__ ovfcnt, const OvfE* __restrict__ ovf,
    const unsigned short* __restrict__ Bpack, const float* __restrict__ bsum,
    float* __restrict__ out, int Nn, int capLog2, int usebf) {
  constexpr int ROWB = 528;
  __shared__ __align__(16) unsigned char Us[64 * ROWB];
  const int t = threadIdx.x;
  const int node0 = blockIdx.x * 64;
  const int lane = t & 63, w = t >> 6;
  const int half = lane >> 5, sl = lane & 31;
  const int cap = 1 << capLog2;

  // degree prefetch for this wave's 16 nodes
  int dall = 0;
  {
    int g = node0 + w * 16 + lane;
    if (lane < 16 && g < Nn) dall = deg[g];
  }
  int ovn = 0;
  if (__any(dall > cap)) ovn = *ovfcnt;   // cold path only

  for (int ii = 0; ii < 8; ++ii) {
    int nodeIdx = ii * 2 + half;
    int g = node0 + w * 16 + nodeIdx;
    int dv = __shfl(dall, nodeIdx);
    f32x4 acc = {0.f, 0.f, 0.f, 0.f};
    if (g < Nn && dv > 0) {
      int d = min(dv, cap);
      const int2* sb = slots + ((size_t)g << capLog2);
      if (usebf) {
        for (int p = 0; p < d; p += 8) {
          int2 e[8];
          #pragma unroll
          for (int q = 0; q < 8; ++q) e[q] = sb[min(p + q, d - 1)];
          uint2 v[8];
          #pragma unroll
          for (int q = 0; q < 8; ++q)
            v[q] = *(const uint2*)(xbf + (size_t)e[q].x * D + sl * 4);
          #pragma unroll
          for (int q = 0; q < 8; ++q) {
            float wt = (p + q < d) ? __int_as_float(e[q].y) : 0.f;
            acc[0] += wt * __uint_as_float(v[q].x << 16);
            acc[1] += wt * __uint_as_float(v[q].x & 0xffff0000u);
            acc[2] += wt * __uint_as_float(v[q].y << 16);
            acc[3] += wt * __uint_as_float(v[q].y & 0xffff0000u);
          }
        }
      } else {
        for (int p = 0; p < d; p += 8) {
          int2 e[8];
          #pragma unroll
          for (int q = 0; q < 8; ++q) e[q] = sb[min(p + q, d - 1)];
          float4 v[8];
          #pragma unroll
          for (int q = 0; q < 8; ++q)
            v[q] = ((const float4*)(x + (size_t)e[q].x * D))[sl];
          #pragma unroll
          for (int q = 0; q < 8; ++q) {
            float wt = (p + q < d) ? __int_as_float(e[q].y) : 0.f;
            acc[0] += wt * v[q].x;
            acc[1] += wt * v[q].y;
            acc[2] += wt * v[q].z;
            acc[3] += wt * v[q].w;
          }
        }
      }
      if (dv > cap) {   // correctness fallback, ~never taken
        for (int j = 0; j < ovn; ++j) {
          if (ovf[j].dst == g) {
            float wt = ovf[j].w;
            int r = ovf[j].row;
            if (usebf) {
              uint2 v = *(const uint2*)(xbf + (size_t)r * D + sl * 4);
              acc[0] += wt * __uint_as_float(v.x << 16);
              acc[1] += wt * __uint_as_float(v.x & 0xffff0000u);
              acc[2] += wt * __uint_as_float(v.y << 16);
              acc[3] += wt * __uint_as_float(v.y & 0xffff0000u);
            } else {
              float4 v = ((const float4*)(x + (size_t)r * D))[sl];
              acc[0] += wt * v.x; acc[1] += wt * v.y;
              acc[2] += wt * v.z; acc[3] += wt * v.w;
            }
          }
        }
      }
    }
    float4 xr = make_float4(0.f, 0.f, 0.f, 0.f);
    if (g < Nn) xr = ((const float4*)(x + (size_t)g * D))[sl];
    uint2 up, vp;
    up.x = f2bf(acc[0] + xr.x) | (f2bf(acc[1] + xr.y) << 16);
    up.y = f2bf(acc[2] + xr.z) | (f2bf(acc[3] + xr.w) << 16);
    vp.x = f2bf(acc[0] * xr.x) | (f2bf(acc[1] * xr.y) << 16);
    vp.y = f2bf(acc[2] * xr.z) | (f2bf(acc[3] * xr.w) << 16);
    int nrow = w * 16 + nodeIdx;
    *(uint2*)(Us + nrow * ROWB + sl * 8)       = up;   // u: k 0..127
    *(uint2*)(Us + nrow * ROWB + 256 + sl * 8) = vp;   // v: k 128..255
  }
  __syncthreads();

  // ---- phase 2: MFMA
  const int c15 = lane & 15, kq = lane >> 4;

  short8 afr[8];
  const unsigned char* abase = Us + (size_t)(w * 16 + c15) * ROWB + kq * 16;
  #pragma unroll
  for (int kt = 0; kt < 8; ++kt)
    afr[kt] = *(const short8*)(abase + kt * 64);

  f32x4 acc2[8];
  #pragma unroll
  for (int nt = 0; nt < 8; ++nt) acc2[nt] = (f32x4){0.f, 0.f, 0.f, 0.f};

  const short8* bp = (const short8*)Bpack + lane;
  #pragma unroll
  for (int kt = 0; kt < 8; ++kt) {
    #pragma unroll
    for (int nt = 0; nt < 8; ++nt) {
      short8 bfr = bp[(kt * 8 + nt) * 64];
      acc2[nt] = __builtin_amdgcn_mfma_f32_16x16x32_bf16(afr[kt], bfr, acc2[nt], 0, 0, 0);
    }
  }

  float bsv[8];
  #pragma unroll
  for (int nt = 0; nt < 8; ++nt) bsv[nt] = bsum[nt * 16 + c15];

  #pragma unroll
  for (int r = 0; r < 4; ++r) {
    int g = node0 + w * 16 + kq * 4 + r;
    if (g >= Nn) continue;
    float* orow = out + (size_t)g * D + c15;
    #pragma unroll
    for (int nt = 0; nt < 8; ++nt) {
      float h = acc2[nt][r] + bsv[nt];
      orow[nt * 16] = h > 0.f ? h : 0.2f * h;
    }
  }
}

// ---------------------------------------------------------------------------
extern "C" void kernel_launch(void* const* d_in, const int* in_sizes, int n_in,
                              void* d_out, int out_size, void* d_ws, size_t ws_size,
                              hipStream_t stream) {
  const float* x  = (const float*)d_in[0];
  const int*   ei = (const int*)d_in[1];
  const float* ew = (const float*)d_in[2];
  const float* W1 = (const float*)d_in[3];
  const float* b1 = (const float*)d_in[4];
  const float* W2 = (const float*)d_in[5];
  const float* b2 = (const float*)d_in[6];
  float* out = (float*)d_out;

  const int Nn = in_sizes[0] / D;   // 100000
  const int E  = in_sizes[2];       // 600000
  const int n8 = Nn * D / 8;

  auto al = [](size_t v) { return (v + 255) & ~(size_t)255; };
  const int ovfcap = 65536;
  const size_t degB   = al((size_t)(Nn + 1) * 4);   // deg[Nn] + ovfcnt at [Nn]
  const size_t ovfB   = al((size_t)ovfcap * sizeof(OvfE));
  const size_t BpackB = 65536;
  const size_t bsB    = 512;
  const size_t xbfB   = al((size_t)Nn * D * 2);
  const size_t fixedB = degB + ovfB + BpackB + bsB;

  // tier selection: largest slot cap that fits ws (with bf16 gather buffer)
  int capLog2, usebf;
  if      (ws_size >= fixedB + (((size_t)Nn << 5) * 8) + xbfB) { capLog2 = 5; usebf = 1; }
  else if (ws_size >= fixedB + (((size_t)Nn << 4) * 8) + xbfB) { capLog2 = 4; usebf = 1; }
  else if (ws_size >= fixedB + (((size_t)Nn << 4) * 8))        { capLog2 = 4; usebf = 0; }
  else                                                         { capLog2 = 3; usebf = 0; }
  const size_t slotsB = al(((size_t)Nn << capLog2) * 8);

  char* base = (char*)d_ws;
  int*  deg    = (int*)base;                      base += degB;
  OvfE* ovf    = (OvfE*)base;                     base += ovfB;
  unsigned short* Bpack = (unsigned short*)base;  base += BpackB;
  float* bs    = (float*)base;                    base += bsB;
  int2* slots  = (int2*)base;                     base += slotsB;
  unsigned short* xbf = (unsigned short*)base;

  hipMemsetAsync(deg, 0, (size_t)(Nn + 1) * 4, stream);

  const int XB = usebf ? (n8 + 255) / 256 : 0;
  const int FB = (E + 255) / 256;
  pre_k<<<XB + FB + 128, 256, 0, stream>>>(
      x, xbf, n8, XB, ei, ew, deg, deg + Nn, slots, ovf, ovfcap,
      capLog2, E, FB, W1, b1, W2, b2, Bpack, bs);

  aggfused_k<<<(Nn + 63) / 64, 256, 0, stream>>>(
      usebf ? xbf : (const unsigned short*)nullptr, x, deg, slots,
      deg + Nn, ovf, Bpack, bs, out, Nn, capLog2, usebf);
}

// Round 8
// 205.585 us; speedup vs baseline: 1.2343x; 1.0641x over previous
//
#include <hip/hip_runtime.h>

#define D 128

typedef __attribute__((ext_vector_type(8))) short short8;
typedef __attribute__((ext_vector_type(4))) float f32x4;

struct OvfE { int dst, row; float w; };

__device__ __forceinline__ unsigned int f2bf(float f) {
  unsigned int u = __float_as_uint(f);
  return (u + 0x7fffu + ((u >> 16) & 1u)) >> 16;   // RNE to bf16
}
__device__ __forceinline__ float bfl(unsigned int u) {
  return __uint_as_float(u << 16);
}
__device__ __forceinline__ float bfh(unsigned int u) {
  return __uint_as_float(u & 0xffff0000u);
}

// ---------------------------------------------------------------------------
// pre: blocks [0,XB) x->bf16 | [XB,XB+FB) slot-fill | [XB+FB,+128) W-pack/bias
// ---------------------------------------------------------------------------
__global__ __launch_bounds__(256) void pre_k(
    const float* __restrict__ x, unsigned short* __restrict__ xbf, int n8, int XB,
    const int* __restrict__ ei, const float* __restrict__ ew,
    int* __restrict__ deg, int* __restrict__ ovfcnt,
    int2* __restrict__ slots, OvfE* __restrict__ ovf, int ovfcap,
    int capLog2, int E, int FB,
    const float* __restrict__ W1, const float* __restrict__ b1,
    const float* __restrict__ W2, const float* __restrict__ b2,
    unsigned short* __restrict__ Bpack, float* __restrict__ bsum) {
  int b = blockIdx.x;
  if (b < XB) {
    int tid = b * 256 + threadIdx.x;
    if (tid >= n8) return;
    float4 a = ((const float4*)x)[(size_t)tid * 2];
    float4 c = ((const float4*)x)[(size_t)tid * 2 + 1];
    uint4 o;
    o.x = f2bf(a.x) | (f2bf(a.y) << 16);
    o.y = f2bf(a.z) | (f2bf(a.w) << 16);
    o.z = f2bf(c.x) | (f2bf(c.y) << 16);
    o.w = f2bf(c.z) | (f2bf(c.w) << 16);
    ((uint4*)xbf)[tid] = o;
  } else if (b < XB + FB) {
    int e = (b - XB) * 256 + threadIdx.x;
    if (e >= E) return;
    int c = ei[E + e];
    int p = atomicAdd(&deg[c], 1);
    if (p < (1 << capLog2)) {
      slots[((size_t)c << capLog2) + p] = make_int2(ei[e], __float_as_int(ew[e]));
    } else {
      int oi = atomicAdd(ovfcnt, 1);
      if (oi < ovfcap) { ovf[oi].dst = c; ovf[oi].row = ei[e]; ovf[oi].w = ew[e]; }
    }
  } else {
    int tid = (b - XB - FB) * 256 + threadIdx.x;   // 0..32767
    if (tid < 32768) {
      int j = tid & 7;
      int l = (tid >> 3) & 63;
      int ktnt = tid >> 9;
      int kt = ktnt >> 3, nt = ktnt & 7;
      int k = kt * 32 + ((l >> 4) << 3) + j;
      int col = nt * 16 + (l & 15);
      float v = (k < 128) ? W1[col * 128 + k] : W2[col * 128 + (k - 128)];
      Bpack[tid] = (unsigned short)f2bf(v);
    }
    if (tid < 128) bsum[tid] = b1[tid] + b2[tid];
  }
}

// ---------------------------------------------------------------------------
// aggfused: 64-node tile, 4 waves x 16 nodes. Phase 1: QUARTER-wave (16 lanes
// x uint4 bf16 = 16B) per node -> 4 nodes in flight per wave; batch-0 of 8
// edges is unconditional (weight-masked, index-clamped) with descriptors for
// all 4 nodes hoisted before any gathers; tail batches rare. Phase 2: each
// wave's MFMA reads only its OWN 16 LDS rows -> NO __syncthreads needed.
// LDS row: [0,256)=u, [256,512)=v; ROWB=528. A: row=lane&15, k=(lane>>4)*8+j.
// C: col=lane&15, row=(lane>>4)*4+r (m89-verified).
// ---------------------------------------------------------------------------
__global__ __launch_bounds__(256, 4) void aggfused_k(
    const unsigned short* __restrict__ xbf, const float* __restrict__ x,
    const int* __restrict__ deg, const int2* __restrict__ slots,
    const int* __restrict__ ovfcnt, const OvfE* __restrict__ ovf,
    const unsigned short* __restrict__ Bpack, const float* __restrict__ bsum,
    float* __restrict__ out, int Nn, int capLog2) {
  constexpr int ROWB = 528;
  __shared__ __align__(16) unsigned char Us[64 * ROWB];
  const int t = threadIdx.x;
  const int node0 = blockIdx.x * 64;
  const int lane = t & 63, w = t >> 6;
  const int q = lane >> 4, ql = lane & 15;
  const int cap = 1 << capLog2;

  // degree prefetch for this wave's 16 nodes
  int dall = 0;
  {
    int g = node0 + w * 16 + lane;
    if (lane < 16 && g < Nn) dall = deg[g];
  }
  int ovn = 0;
  if (__any(dall > cap)) ovn = *ovfcnt;   // cold path only

  // per-quarter node state
  int dv[4], gg[4];
  const int2* sb[4];
  #pragma unroll
  for (int ii = 0; ii < 4; ++ii) {
    int nodeIdx = ii * 4 + q;
    int g = node0 + w * 16 + nodeIdx;
    dv[ii] = __shfl(dall, nodeIdx);
    gg[ii] = g;
    sb[ii] = slots + ((size_t)min(g, Nn - 1) << capLog2);
  }

  // pass A: hoist batch-0 descriptors for all 4 nodes
  int2 e0[4][8];
  #pragma unroll
  for (int ii = 0; ii < 4; ++ii) {
    int dm = max(dv[ii] - 1, 0);
    #pragma unroll
    for (int j = 0; j < 8; ++j) e0[ii][j] = sb[ii][min(j, dm)];
  }

  // pass B: gather + accumulate + stage per node
  #pragma unroll
  for (int ii = 0; ii < 4; ++ii) {
    float acc[8] = {0.f, 0.f, 0.f, 0.f, 0.f, 0.f, 0.f, 0.f};
    {
      uint4 v[8];
      #pragma unroll
      for (int j = 0; j < 8; ++j) {
        int r = min(max(e0[ii][j].x, 0), Nn - 1);   // sanitize (poisoned ws)
        v[j] = *(const uint4*)(xbf + (size_t)r * D + ql * 8);
      }
      #pragma unroll
      for (int j = 0; j < 8; ++j) {
        float wt = (j < dv[ii]) ? __int_as_float(e0[ii][j].y) : 0.f;
        acc[0] += wt * bfl(v[j].x); acc[1] += wt * bfh(v[j].x);
        acc[2] += wt * bfl(v[j].y); acc[3] += wt * bfh(v[j].y);
        acc[4] += wt * bfl(v[j].z); acc[5] += wt * bfh(v[j].z);
        acc[6] += wt * bfl(v[j].w); acc[7] += wt * bfh(v[j].w);
      }
    }
    // tail batches (deg > 8; ~15% of nodes)
    for (int p = 8; p < dv[ii]; p += 8) {
      int2 e2[8];
      #pragma unroll
      for (int j = 0; j < 8; ++j) e2[j] = sb[ii][min(p + j, dv[ii] - 1)];
      uint4 v2[8];
      #pragma unroll
      for (int j = 0; j < 8; ++j) {
        int r = min(max(e2[j].x, 0), Nn - 1);
        v2[j] = *(const uint4*)(xbf + (size_t)r * D + ql * 8);
      }
      #pragma unroll
      for (int j = 0; j < 8; ++j) {
        float wt = (p + j < dv[ii]) ? __int_as_float(e2[j].y) : 0.f;
        acc[0] += wt * bfl(v2[j].x); acc[1] += wt * bfh(v2[j].x);
        acc[2] += wt * bfl(v2[j].y); acc[3] += wt * bfh(v2[j].y);
        acc[4] += wt * bfl(v2[j].z); acc[5] += wt * bfh(v2[j].z);
        acc[6] += wt * bfl(v2[j].w); acc[7] += wt * bfh(v2[j].w);
      }
    }
    // overflow fallback (~never taken)
    if (dv[ii] > cap) {
      for (int jj = 0; jj < ovn; ++jj) {
        if (ovf[jj].dst == gg[ii]) {
          float wt = ovf[jj].w;
          int r = ovf[jj].row;
          uint4 v = *(const uint4*)(xbf + (size_t)r * D + ql * 8);
          acc[0] += wt * bfl(v.x); acc[1] += wt * bfh(v.x);
          acc[2] += wt * bfl(v.y); acc[3] += wt * bfh(v.y);
          acc[4] += wt * bfl(v.z); acc[5] += wt * bfh(v.z);
          acc[6] += wt * bfl(v.w); acc[7] += wt * bfh(v.w);
        }
      }
    }
    // u,v from fp32 x; pack bf16; stage to this wave's private LDS rows
    float4 xa = make_float4(0.f, 0.f, 0.f, 0.f), xb = xa;
    if (gg[ii] < Nn) {
      const float4* xr = (const float4*)(x + (size_t)gg[ii] * D);
      xa = xr[ql * 2];
      xb = xr[ql * 2 + 1];
    }
    uint4 up, vp;
    up.x = f2bf(acc[0] + xa.x) | (f2bf(acc[1] + xa.y) << 16);
    up.y = f2bf(acc[2] + xa.z) | (f2bf(acc[3] + xa.w) << 16);
    up.z = f2bf(acc[4] + xb.x) | (f2bf(acc[5] + xb.y) << 16);
    up.w = f2bf(acc[6] + xb.z) | (f2bf(acc[7] + xb.w) << 16);
    vp.x = f2bf(acc[0] * xa.x) | (f2bf(acc[1] * xa.y) << 16);
    vp.y = f2bf(acc[2] * xa.z) | (f2bf(acc[3] * xa.w) << 16);
    vp.z = f2bf(acc[4] * xb.x) | (f2bf(acc[5] * xb.y) << 16);
    vp.w = f2bf(acc[6] * xb.z) | (f2bf(acc[7] * xb.w) << 16);
    int nrow = w * 16 + ii * 4 + q;
    *(uint4*)(Us + nrow * ROWB + ql * 16)       = up;   // u: k 0..127
    *(uint4*)(Us + nrow * ROWB + 256 + ql * 16) = vp;   // v: k 128..255
  }

  // ---- phase 2: MFMA (reads only this wave's own LDS rows -> no barrier)
  const int c15 = lane & 15, kq = lane >> 4;

  short8 afr[8];
  const unsigned char* abase = Us + (size_t)(w * 16 + c15) * ROWB + kq * 16;
  #pragma unroll
  for (int kt = 0; kt < 8; ++kt)
    afr[kt] = *(const short8*)(abase + kt * 64);

  f32x4 acc2[8];
  #pragma unroll
  for (int nt = 0; nt < 8; ++nt) acc2[nt] = (f32x4){0.f, 0.f, 0.f, 0.f};

  const short8* bp = (const short8*)Bpack + lane;
  #pragma unroll
  for (int kt = 0; kt < 8; ++kt) {
    #pragma unroll
    for (int nt = 0; nt < 8; ++nt) {
      short8 bfr = bp[(kt * 8 + nt) * 64];
      acc2[nt] = __builtin_amdgcn_mfma_f32_16x16x32_bf16(afr[kt], bfr, acc2[nt], 0, 0, 0);
    }
  }

  float bsv[8];
  #pragma unroll
  for (int nt = 0; nt < 8; ++nt) bsv[nt] = bsum[nt * 16 + c15];

  #pragma unroll
  for (int r = 0; r < 4; ++r) {
    int g = node0 + w * 16 + kq * 4 + r;
    if (g >= Nn) continue;
    float* orow = out + (size_t)g * D + c15;
    #pragma unroll
    for (int nt = 0; nt < 8; ++nt) {
      float h = acc2[nt][r] + bsv[nt];
      orow[nt * 16] = h > 0.f ? h : 0.2f * h;
    }
  }
}

// ---------------------------------------------------------------------------
extern "C" void kernel_launch(void* const* d_in, const int* in_sizes, int n_in,
                              void* d_out, int out_size, void* d_ws, size_t ws_size,
                              hipStream_t stream) {
  const float* x  = (const float*)d_in[0];
  const int*   ei = (const int*)d_in[1];
  const float* ew = (const float*)d_in[2];
  const float* W1 = (const float*)d_in[3];
  const float* b1 = (const float*)d_in[4];
  const float* W2 = (const float*)d_in[5];
  const float* b2 = (const float*)d_in[6];
  float* out = (float*)d_out;

  const int Nn = in_sizes[0] / D;   // 100000
  const int E  = in_sizes[2];       // 600000
  const int n8 = Nn * D / 8;

  auto al = [](size_t v) { return (v + 255) & ~(size_t)255; };
  const int ovfcap = 65536;
  const size_t degB   = al((size_t)(Nn + 1) * 4);   // deg[Nn] + ovfcnt at [Nn]
  const size_t ovfB   = al((size_t)ovfcap * sizeof(OvfE));
  const size_t BpackB = 65536;
  const size_t bsB    = 512;
  const size_t xbfB   = al((size_t)Nn * D * 2);
  const size_t fixedB = degB + ovfB + BpackB + bsB;

  // largest slot cap that fits ws (bf16 gather buffer required)
  int capLog2;
  if      (ws_size >= fixedB + (((size_t)Nn << 5) * 8) + xbfB) capLog2 = 5;
  else if (ws_size >= fixedB + (((size_t)Nn << 4) * 8) + xbfB) capLog2 = 4;
  else                                                         capLog2 = 3;
  const size_t slotsB = al(((size_t)Nn << capLog2) * 8);

  char* base = (char*)d_ws;
  int*  deg    = (int*)base;                      base += degB;
  OvfE* ovf    = (OvfE*)base;                     base += ovfB;
  unsigned short* Bpack = (unsigned short*)base;  base += BpackB;
  float* bs    = (float*)base;                    base += bsB;
  int2* slots  = (int2*)base;                     base += slotsB;
  unsigned short* xbf = (unsigned short*)base;

  hipMemsetAsync(deg, 0, (size_t)(Nn + 1) * 4, stream);

  const int XB = (n8 + 255) / 256;
  const int FB = (E + 255) / 256;
  pre_k<<<XB + FB + 128, 256, 0, stream>>>(
      x, xbf, n8, XB, ei, ew, deg, deg + Nn, slots, ovf, ovfcap,
      capLog2, E, FB, W1, b1, W2, b2, Bpack, bs);

  aggfused_k<<<(Nn + 63) / 64, 256, 0, stream>>>(
      xbf, x, deg, slots, deg + Nn, ovf, Bpack, bs, out, Nn, capLog2);
}